// Round 1
// 105.025 us; speedup vs baseline: 1.0049x; 1.0049x over previous
//
#include <hip/hip_runtime.h>

#define S_DIM 16
#define T_DIM 12
#define BLOCK 256
#define YROW  17   // 16 species + constant-1.0 slot; odd stride -> only 2-way bank aliasing (free)

__global__ __launch_bounds__(BLOCK) void mech_kernel(
    const float* __restrict__ y,        // (B,16) f32
    const float* __restrict__ fr,       // (B,12) f32
    const float* __restrict__ rr,       // (B,12) f32
    const float* __restrict__ stoich,   // (12,16) f32, entries in {-1,0,1}
    const float* __restrict__ effects,  // (12,16) f32
    const int* __restrict__ from_idx,
    const int* __restrict__ from_valid,
    const int* __restrict__ to_idx,
    const int* __restrict__ to_valid,
    const int* __restrict__ reversible,
    float* __restrict__ out,            // (B,16) f32
    int nb)
{
    __shared__ float s_y[BLOCK * YROW];
    __shared__ int   s_si[T_DIM], s_fi[T_DIM], s_pi[T_DIM], s_ti[T_DIM];
    __shared__ float s_rg[T_DIM];

    const int tid = threadIdx.x;
    const long long base_row = (long long)blockIdx.x * BLOCK;
    const bool full = (base_row + BLOCK) <= (long long)nb;   // block-uniform

    // Per-block decode of the tiny mechanism index tables (first 12 threads).
    // Mechanism guarantees: each stoich row has exactly one -1 (substrate)
    // and at most one +1 (product), so sub_conc = y[sub], prod_conc = y[prod]|1.
    if (tid < T_DIM) {
        int sub = 16, prod = 16;          // 16 -> constant-1.0 slot
        #pragma unroll
        for (int s = 0; s < S_DIM; ++s) {
            float v = stoich[tid * S_DIM + s];
            if (v < -0.5f) sub = s;
            if (v >  0.5f) prod = s;
        }
        s_si[tid] = sub;
        s_pi[tid] = prod;
        s_fi[tid] = from_valid[tid] ? from_idx[tid] : 16;
        s_ti[tid] = to_valid[tid]   ? to_idx[tid]   : 16;
        s_rg[tid] = reversible[tid] ? 1.0f : 0.0f;
    }

    const int b  = (int)base_row + tid;
    const int bc = (b < nb) ? b : 0;

    // ---- Stage y into LDS ----
    if (full) {
        // Cooperative, fully-coalesced: wave reads 1KB contiguous per float4 load.
        const float4* yb = (const float4*)(y + (size_t)base_row * S_DIM);
        #pragma unroll
        for (int k = 0; k < 4; ++k) {
            int i4  = k * BLOCK + tid;          // float4 index in the 256x16 tile
            float4 v = yb[i4];
            float* d = &s_y[(i4 >> 2) * YROW + (i4 & 3) * 4];  // row = i4/4, quarter = i4%4
            d[0] = v.x; d[1] = v.y; d[2] = v.z; d[3] = v.w;
        }
    } else {
        // Tail block: per-thread guarded row load (64B-stride, rare path).
        const float4* yp = (const float4*)(y + (size_t)bc * S_DIM);
        float4 y0 = yp[0], y1 = yp[1], y2 = yp[2], y3 = yp[3];
        float* m = &s_y[tid * YROW];
        m[0]  = y0.x; m[1]  = y0.y; m[2]  = y0.z; m[3]  = y0.w;
        m[4]  = y1.x; m[5]  = y1.y; m[6]  = y1.z; m[7]  = y1.w;
        m[8]  = y2.x; m[9]  = y2.y; m[10] = y2.z; m[11] = y2.w;
        m[12] = y3.x; m[13] = y3.y; m[14] = y3.z; m[15] = y3.w;
    }
    s_y[tid * YROW + 16] = 1.0f;

    // Rate rows: 12 f32 = 48B, byte offset 48*bc is 16B-aligned -> 3x float4.
    // Lines are fully consumed across the wave's 3 loads; keep in registers.
    const float4* fp = (const float4*)(fr + (size_t)bc * T_DIM);
    const float4* rp = (const float4*)(rr + (size_t)bc * T_DIM);
    float4 f0 = fp[0], f1 = fp[1], f2 = fp[2];
    float4 r0 = rp[0], r1 = rp[1], r2 = rp[2];
    const float frv[T_DIM] = {f0.x, f0.y, f0.z, f0.w, f1.x, f1.y, f1.z, f1.w, f2.x, f2.y, f2.z, f2.w};
    const float rrv[T_DIM] = {r0.x, r0.y, r0.z, r0.w, r1.x, r1.y, r1.z, r1.w, r2.x, r2.y, r2.z, r2.w};

    __syncthreads();

    const float* myY = &s_y[tid * YROW];

    float acc[S_DIM];
    #pragma unroll
    for (int s = 0; s < S_DIM; ++s) acc[s] = 0.0f;

    // effects is block-uniform read-only with compile-time indices ->
    // uniform-address float4 loads (scalar path / constant cache), NOT LDS.
    const float4* e4 = (const float4*)effects;

    #pragma unroll
    for (int t = 0; t < T_DIM; ++t) {
        // v_fwd = fr * enz_f * sub_conc ; v_rev = rev ? rr * enz_r * prod_conc : 0
        float vf = frv[t] * myY[s_fi[t]] * myY[s_si[t]];
        float vr = s_rg[t] * rrv[t] * myY[s_ti[t]] * myY[s_pi[t]];
        float v  = vf - vr;

        float4 e0 = e4[t * 4 + 0];
        float4 e1 = e4[t * 4 + 1];
        float4 e2 = e4[t * 4 + 2];
        float4 e3 = e4[t * 4 + 3];
        acc[0]  = fmaf(v, e0.x, acc[0]);  acc[1]  = fmaf(v, e0.y, acc[1]);
        acc[2]  = fmaf(v, e0.z, acc[2]);  acc[3]  = fmaf(v, e0.w, acc[3]);
        acc[4]  = fmaf(v, e1.x, acc[4]);  acc[5]  = fmaf(v, e1.y, acc[5]);
        acc[6]  = fmaf(v, e1.z, acc[6]);  acc[7]  = fmaf(v, e1.w, acc[7]);
        acc[8]  = fmaf(v, e2.x, acc[8]);  acc[9]  = fmaf(v, e2.y, acc[9]);
        acc[10] = fmaf(v, e2.z, acc[10]); acc[11] = fmaf(v, e2.w, acc[11]);
        acc[12] = fmaf(v, e3.x, acc[12]); acc[13] = fmaf(v, e3.y, acc[13]);
        acc[14] = fmaf(v, e3.z, acc[14]); acc[15] = fmaf(v, e3.w, acc[15]);
    }

    // ---- Drain acc through LDS for coalesced stores ----
    // Each thread only ever read its OWN s_y row above, so overwriting it with
    // acc needs no barrier; the cooperative drain below reads other rows -> barrier.
    #pragma unroll
    for (int s = 0; s < S_DIM; ++s) s_y[tid * YROW + s] = acc[s];
    __syncthreads();

    if (full) {
        float4* ob = (float4*)(out + (size_t)base_row * S_DIM);
        #pragma unroll
        for (int k = 0; k < 4; ++k) {
            int i4 = k * BLOCK + tid;
            const float* sp = &s_y[(i4 >> 2) * YROW + (i4 & 3) * 4];
            ob[i4] = make_float4(sp[0], sp[1], sp[2], sp[3]);
        }
    } else if (b < nb) {
        float4* op = (float4*)(out + (size_t)bc * S_DIM);
        op[0] = make_float4(acc[0],  acc[1],  acc[2],  acc[3]);
        op[1] = make_float4(acc[4],  acc[5],  acc[6],  acc[7]);
        op[2] = make_float4(acc[8],  acc[9],  acc[10], acc[11]);
        op[3] = make_float4(acc[12], acc[13], acc[14], acc[15]);
    }
}

extern "C" void kernel_launch(void* const* d_in, const int* in_sizes, int n_in,
                              void* d_out, int out_size, void* d_ws, size_t ws_size,
                              hipStream_t stream) {
    // setup_inputs order:
    // 0: t (f32 scalar, unused)
    // 1: y (B,16) f32        2: forward_rates (B,12) f32   3: reverse_rates (B,12) f32
    // 4: stoich (12,16) f32  5: effects (12,16) f32
    // 6: from_idx int32      7: from_valid int32(bool)
    // 8: to_idx int32        9: to_valid int32(bool)       10: reversible int32(bool)
    const float* y  = (const float*)d_in[1];
    const float* fr = (const float*)d_in[2];
    const float* rr = (const float*)d_in[3];
    const float* st = (const float*)d_in[4];
    const float* ef = (const float*)d_in[5];
    const int* fi = (const int*)d_in[6];
    const int* fv = (const int*)d_in[7];
    const int* ti = (const int*)d_in[8];
    const int* tv = (const int*)d_in[9];
    const int* rv = (const int*)d_in[10];
    float* o = (float*)d_out;

    int nb = in_sizes[1] / S_DIM;   // batch count
    int grid = (nb + BLOCK - 1) / BLOCK;
    mech_kernel<<<grid, BLOCK, 0, stream>>>(y, fr, rr, st, ef, fi, fv, ti, tv, rv, o, nb);
}